// Round 8
// baseline (197.984 us; speedup 1.0000x reference)
//
#include <hip/hip_runtime.h>
#include <math.h>

// B=2, T=2048, D=1024, H=16, DH=64, M=B*T=4096
typedef __attribute__((ext_vector_type(8))) short short8;
typedef __attribute__((ext_vector_type(4))) float f32x4;

static __device__ __forceinline__ unsigned short f2bf(float f) {
  unsigned u = __builtin_bit_cast(unsigned, f);
  u += 0x7fffu + ((u >> 16) & 1u);  // RNE
  return (unsigned short)(u >> 16);
}
static __device__ __forceinline__ float bf2f(unsigned short h) {
  return __builtin_bit_cast(float, ((unsigned)h) << 16);
}
static __device__ __forceinline__ unsigned pack2bf(float a, float b) {
  return (unsigned)f2bf(a) | ((unsigned)f2bf(b) << 16);
}
// truncation pack (1 v_perm_b32): lo = trunc_bf16(a), hi = trunc_bf16(b)
static __device__ __forceinline__ unsigned pack2bf_t(float a, float b) {
  return __builtin_amdgcn_perm(__builtin_bit_cast(unsigned, b),
                               __builtin_bit_cast(unsigned, a), 0x07060302u);
}

typedef __attribute__((address_space(3))) unsigned short lds_us;
typedef __attribute__((address_space(1))) const unsigned short gbl_us;

static __device__ __forceinline__ void gld_lds16(const unsigned short* g,
                                                 unsigned short* l) {
  __builtin_amdgcn_global_load_lds((gbl_us*)g, (lds_us*)l, 16, 0, 0);
}

// ---------------------------------------------------------------------------
// prep: fused input conversion.
//  blocks [0,2048):    cast_x  fp32 x[4096*1024] -> bf16 xb
//  blocks [2048,2816): tcast   qkv_w [1024][3072] -> wqkvT [3072][1024]
//  blocks [2816,3072): tcast   out_w [1024][1024] -> woT  [1024][1024]
// ---------------------------------------------------------------------------
__global__ __launch_bounds__(256) void prep(const float* __restrict__ x,
                                            unsigned short* __restrict__ xb,
                                            const float* __restrict__ qkv_w,
                                            unsigned short* __restrict__ wqkvT,
                                            const float* __restrict__ out_w,
                                            unsigned short* __restrict__ woT) {
  __shared__ unsigned short T[64][68];
  const int blk = blockIdx.x;
  if (blk < 2048) {
    int i = (blk * 256 + threadIdx.x) * 8;
    float4 a = *(const float4*)(x + i);
    float4 b = *(const float4*)(x + i + 4);
    ushort4 u0 = {f2bf(a.x), f2bf(a.y), f2bf(a.z), f2bf(a.w)};
    ushort4 u1 = {f2bf(b.x), f2bf(b.y), f2bf(b.z), f2bf(b.w)};
    *(ushort4*)(xb + i) = u0;
    *(ushort4*)(xb + i + 4) = u1;
    return;
  }
  const float* in;
  unsigned short* out;
  int R, C, bx, by;
  if (blk < 2816) {
    in = qkv_w; out = wqkvT; R = 1024; C = 3072;
    bx = (blk - 2048) % 48; by = (blk - 2048) / 48;
  } else {
    in = out_w; out = woT; R = 1024; C = 1024;
    bx = (blk - 2816) % 16; by = (blk - 2816) / 16;
  }
  const int r0 = by * 64, c0 = bx * 64;
  const int tr = threadIdx.x >> 2;
  const int tc = (threadIdx.x & 3) * 16;
#pragma unroll
  for (int j = 0; j < 4; ++j) {
    float4 v = *(const float4*)(in + (size_t)(r0 + tr) * C + c0 + tc + j * 4);
    ushort4 u = {f2bf(v.x), f2bf(v.y), f2bf(v.z), f2bf(v.w)};
    *(ushort4*)&T[tr][tc + j * 4] = u;
  }
  __syncthreads();
  const int oc = tr;
#pragma unroll
  for (int g = 0; g < 4; ++g) {
    ushort4 u;
    u.x = T[tc + g * 4 + 0][oc];
    u.y = T[tc + g * 4 + 1][oc];
    u.z = T[tc + g * 4 + 2][oc];
    u.w = T[tc + g * 4 + 3][oc];
    *(ushort4*)(out + (size_t)(c0 + oc) * R + r0 + tc + g * 4) = u;
  }
}

// ---------------------------------------------------------------------------
// gemm_qkv512: C[4096,3072] = xb @ wqkvT^T, 128x128 tile, 8 waves (512
// threads), BK=32, double-buffered global_load_lds (1 barrier/iter).
// (R14-proven: same barrier count as R12's 4-wave version, 2x waves/CU.)
// ---------------------------------------------------------------------------
__global__ __launch_bounds__(512) void gemm_qkv512(
    const unsigned short* __restrict__ A, const unsigned short* __restrict__ BT,
    unsigned short* __restrict__ qo, unsigned short* __restrict__ ko,
    unsigned short* __restrict__ vo) {
  __shared__ unsigned short As[2][4096];
  __shared__ unsigned short Bs[2][4096];
  const int tid = threadIdx.x;
  const int w = tid >> 6;
  const int lane = tid & 63;
  const int l15 = lane & 15;
  const int quad = lane >> 4;
  const int wm = w >> 2;       // 0..1 : row half
  const int wn = w & 3;        // 0..3 : column group
  const int m0 = blockIdx.y * 128;
  const int n0 = blockIdx.x * 128;

  f32x4 acc[4][2];
  const f32x4 zero4 = {0.f, 0.f, 0.f, 0.f};
#pragma unroll
  for (int mt = 0; mt < 4; ++mt)
#pragma unroll
    for (int nt = 0; nt < 2; ++nt) acc[mt][nt] = zero4;

  // staging: 512 chunks per matrix, 1 A + 1 B chunk per thread
  const int srow = tid >> 2;
  const int skch = (tid & 3) ^ ((srow >> 1) & 3);
  const int coff = tid * 8;
  const unsigned short* gA = A + (size_t)(m0 + srow) * 1024 + skch * 8;
  const unsigned short* gB = BT + (size_t)(n0 + srow) * 1024 + skch * 8;

  const int swz = (quad ^ ((l15 >> 1) & 3)) * 8;
  int aoff[4], boff[2];
#pragma unroll
  for (int t = 0; t < 4; ++t)
    aoff[t] = (wm * 64 + t * 16 + l15) * 32 + swz;
#pragma unroll
  for (int t = 0; t < 2; ++t)
    boff[t] = ((wn >> 1) * 64 + (wn & 1) * 16 + t * 32 + l15) * 32 + swz;

  auto issue = [&](int k0, int buf) {
    gld_lds16(gA + k0, &As[buf][coff]);
    gld_lds16(gB + k0, &Bs[buf][coff]);
  };

  issue(0, 0);
  for (int it = 0; it < 32; ++it) {
    const int cur = it & 1;
    __syncthreads();  // drains the prefetch issued one full iteration ago
    if (it + 1 < 32) issue((it + 1) * 32, cur ^ 1);

    short8 af[4], bf[2];
#pragma unroll
    for (int t = 0; t < 4; ++t) af[t] = *(const short8*)(&As[cur][aoff[t]]);
#pragma unroll
    for (int t = 0; t < 2; ++t) bf[t] = *(const short8*)(&Bs[cur][boff[t]]);
#pragma unroll
    for (int mt = 0; mt < 4; ++mt)
#pragma unroll
      for (int nt = 0; nt < 2; ++nt)
        acc[mt][nt] =
            __builtin_amdgcn_mfma_f32_16x16x32_bf16(af[mt], bf[nt], acc[mt][nt], 0, 0, 0);
  }

  const int b = m0 >> 11;
  const int ngrp = n0 + (wn >> 1) * 64;  // 64-aligned (which, head) group
  const int which = ngrp >> 10;
  const int h = (ngrp & 1023) >> 6;
  const int bh = b * 16 + h;
  if (which < 2) {
    unsigned short* dst = which ? ko : qo;
    // q pre-scale: 1/sqrt(64) * log2(e) so attention scores feed exp2.
    const float qs = (which == 0) ? 0.1803368801111f : 1.0f;
    const int p = (wn & 1) * 16 + l15;  // RoPE freq index, < 32
    // 10000^(-p/32) / 2pi (angle in revolutions for v_sin/v_cos)
    float inv = __builtin_amdgcn_exp2f((float)p * -0.41524101186f) *
                0.15915494309f;
#pragma unroll
    for (int mt = 0; mt < 4; ++mt)
#pragma unroll
      for (int r = 0; r < 4; ++r) {
        int t = (m0 + wm * 64 + mt * 16 + quad * 4 + r) & 2047;
        float rv = __builtin_amdgcn_fractf((float)t * inv);
        float s = __builtin_amdgcn_sinf(rv);
        float c = __builtin_amdgcn_cosf(rv);
        float x0 = acc[mt][0][r], x1 = acc[mt][1][r];
        size_t rowoff = ((size_t)bh * 2048 + t) * 64;
        dst[rowoff + p]      = f2bf((x0 * c - x1 * s) * qs);
        dst[rowoff + p + 32] = f2bf((x1 * c + x0 * s) * qs);
      }
  } else {
#pragma unroll
    for (int mt = 0; mt < 4; ++mt) {
      int t0 = (m0 + wm * 64 + mt * 16 + quad * 4) & 2047;
#pragma unroll
      for (int nt = 0; nt < 2; ++nt) {
        int dh = (wn & 1) * 16 + nt * 32 + l15;
        ushort4 st = {f2bf(acc[mt][nt][0]), f2bf(acc[mt][nt][1]),
                      f2bf(acc[mt][nt][2]), f2bf(acc[mt][nt][3])};
        *(ushort4*)(vo + ((size_t)bh * 64 + dh) * 2048 + t0) = st;
      }
    }
  }
}

// ---------------------------------------------------------------------------
// gemm_out R21: out[4096,1024] = ab @ woT^T + bias, fp32 store.
// gemm_qkv512 structure: 128x128 tile, 8 waves (512 thr), BK=32, dbuf
// global_load_lds, 1 barrier/iter. Grid (8,32) = 256 blocks = 1/CU.
// R21-proven (+2.4us vs the 128x64 4-wave version).
// ---------------------------------------------------------------------------
__global__ __launch_bounds__(512) void gemm_out(
    const unsigned short* __restrict__ A, const unsigned short* __restrict__ BT,
    const float* __restrict__ bias, float* __restrict__ out) {
  __shared__ unsigned short As[2][4096];
  __shared__ unsigned short Bs[2][4096];
  const int tid = threadIdx.x;
  const int w = tid >> 6;
  const int lane = tid & 63;
  const int l15 = lane & 15;
  const int quad = lane >> 4;
  const int wm = w >> 2;       // 0..1 : row half
  const int wn = w & 3;        // 0..3 : column group
  const int m0 = blockIdx.y * 128;
  const int n0 = blockIdx.x * 128;

  f32x4 acc[4][2];
  const f32x4 zero4 = {0.f, 0.f, 0.f, 0.f};
#pragma unroll
  for (int mt = 0; mt < 4; ++mt)
#pragma unroll
    for (int nt = 0; nt < 2; ++nt) acc[mt][nt] = zero4;

  // staging: 512 chunks per matrix, 1 A + 1 B chunk per thread
  const int srow = tid >> 2;
  const int skch = (tid & 3) ^ ((srow >> 1) & 3);
  const int coff = tid * 8;
  const unsigned short* gA = A + (size_t)(m0 + srow) * 1024 + skch * 8;
  const unsigned short* gB = BT + (size_t)(n0 + srow) * 1024 + skch * 8;

  const int swz = (quad ^ ((l15 >> 1) & 3)) * 8;
  int aoff[4], boff[2];
#pragma unroll
  for (int t = 0; t < 4; ++t)
    aoff[t] = (wm * 64 + t * 16 + l15) * 32 + swz;
#pragma unroll
  for (int t = 0; t < 2; ++t)
    boff[t] = ((wn >> 1) * 64 + (wn & 1) * 16 + t * 32 + l15) * 32 + swz;

  auto issue = [&](int k0, int buf) {
    gld_lds16(gA + k0, &As[buf][coff]);
    gld_lds16(gB + k0, &Bs[buf][coff]);
  };

  issue(0, 0);
  for (int it = 0; it < 32; ++it) {
    const int cur = it & 1;
    __syncthreads();  // drains the prefetch issued one full iteration ago
    if (it + 1 < 32) issue((it + 1) * 32, cur ^ 1);

    short8 af[4], bf[2];
#pragma unroll
    for (int t = 0; t < 4; ++t) af[t] = *(const short8*)(&As[cur][aoff[t]]);
#pragma unroll
    for (int t = 0; t < 2; ++t) bf[t] = *(const short8*)(&Bs[cur][boff[t]]);
#pragma unroll
    for (int mt = 0; mt < 4; ++mt)
#pragma unroll
      for (int nt = 0; nt < 2; ++nt)
        acc[mt][nt] =
            __builtin_amdgcn_mfma_f32_16x16x32_bf16(af[mt], bf[nt], acc[mt][nt], 0, 0, 0);
  }

  // epilogue: cols n = n0 + (wn>>1)*64 + (wn&1)*16 + nt*32 + l15 (matches boff)
  const int nb2 = n0 + (wn >> 1) * 64 + (wn & 1) * 16;
  float bv[2];
#pragma unroll
  for (int nt = 0; nt < 2; ++nt) bv[nt] = bias[nb2 + nt * 32 + l15];
#pragma unroll
  for (int mt = 0; mt < 4; ++mt)
#pragma unroll
    for (int r = 0; r < 4; ++r) {
      int m = m0 + wm * 64 + mt * 16 + quad * 4 + r;
      float* orow = out + (size_t)m * 1024 + nb2 + l15;
      orow[0]  = acc[mt][0][r] + bv[0];
      orow[32] = acc[mt][1][r] + bv[1];
    }
}

// ---------------------------------------------------------------------------
// Causal flash attention, bf16 MFMA. R23: complementary-pair balance.
// R22 post-mortem: no-partials was right (WRITE 21.5->8.2 MB) but the
// 1024-block co-resident grid had static imbalance -- linear id gives CU
// group ybase the qb set {31,23,15,7}-ybase = 160-8*ybase units vs 132
// avg; unit model 160x740cyc = 49us ~= measured 52 (model confirmed again).
// R23 exact fix: block (bh, y) runs TWO passes, qb = 31-y then qb = y.
// Per-block tiles = 2(32-y) + 2(y+1) = 66, CONSTANT in y. 512 blocks,
// 2/CU -> every CU carries exactly 132 units. No partials, no combine,
// direct og writes (proven epilogue). Inter-pass __syncthreads so pass-2
// DMA can't overwrite LDS the partner wave still reads. XCD pinning kept
// (linear%8 = bh%8). Inner loop byte-for-byte R22/R21/R17.
// Predicted: attn ~41-43us (132x740cyc) with R22's traffic savings kept.
// ---------------------------------------------------------------------------
__global__ __launch_bounds__(128, 4) void attn_mfma(
    const unsigned short* __restrict__ qg, const unsigned short* __restrict__ kg,
    const unsigned short* __restrict__ vtg, unsigned short* __restrict__ og) {
  // Ks: [key 32][128B] rows, chunk c holds dh-chunk c^(key&7)
  // Vt: [r 32][128B] rows, chunk c -> lc=c^(r&7): dh=(lc>>2)*32+r, t-chunk lc&3
  // Ps: per-wave [q&15 16][128B], chunk c -> lc=c^(q&7): half lc>>2 = q-group,
  //     key-chunk lc&3 (8 keys, two 8B halves)
  __shared__ unsigned short Ks[2][2048];  // 8192 B
  __shared__ unsigned short Vt[2][2048];  // 8192 B
  __shared__ unsigned short Ps[2][1024];  // 4096 B (per wave 2KB: 32q x 32k)
  const int bh = blockIdx.x;   // x = bh -> XCD = bh%8 (L2 locality)
  const int y = blockIdx.y;    // 0..15; passes handle qb = 31-y, then y

  const int tid = threadIdx.x;
  const int w = tid >> 6;   // 0..1
  const int lane = tid & 63;
  const int l15 = lane & 15;
  const int quad = lane >> 4;
  const int m7 = l15 & 7;
  const int qw = w * 32;  // wave's first query within block

  const f32x4 zero4 = {0.f, 0.f, 0.f, 0.f};
  const short one_bf = (short)0x3F80;  // bf16 1.0
  const short8 ones8 = {one_bf, one_bf, one_bf, one_bf,
                        one_bf, one_bf, one_bf, one_bf};

  const unsigned short* kbase = kg + (size_t)bh * 2048 * 64;
  const unsigned short* vtbase = vtg + (size_t)bh * 64 * 2048;
  unsigned short* pb = Ps[w];

  // staging: 256 16B-chunks per matrix, 2 K + 2 V per thread (128 threads)
  int doff[2], koff[2], voff[2];
#pragma unroll
  for (int i = 0; i < 2; ++i) {
    int d = i * 128 + tid;
    doff[i] = d * 8;
    int r = d >> 3;
    int lc = (d & 7) ^ (r & 7);
    koff[i] = r * 64 + lc * 8;               // key r, dh-chunk lc
    int dh = (lc >> 2) * 32 + r;
    voff[i] = dh * 2048 + (lc & 3) * 8;      // dh row, t-chunk lc&3
  }

  auto issue = [&](int kb, int buf) {
#pragma unroll
    for (int i = 0; i < 2; ++i) {
      gld_lds16(kbase + kb * 2048 + koff[i], &Ks[buf][doff[i]]);
      gld_lds16(vtbase + voff[i] + kb * 32, &Vt[buf][doff[i]]);
    }
  };

  const int kc0 = ((quad ^ m7) & 7) * 8;  // K chunk for dh=quad*8
  const int kc1 = kc0 ^ 32;               // K chunk for dh=quad*8+32
  int prd[2], vch[2];
#pragma unroll
  for (int g = 0; g < 2; ++g) prd[g] = l15 * 64 + (((g << 2) | quad) ^ m7) * 8;
#pragma unroll
  for (int h = 0; h < 2; ++h) vch[h] = (((h << 2) | quad) ^ m7) * 8;

  for (int pass = 0; pass < 2; ++pass) {
    const int qb = pass == 0 ? 31 - y : y;  // heavy first
    const int t1 = 2 * (qb + 1);
    const int gq0 = qb * 64;

    // Q fragments for two 16-query groups
    short8 qf[2][2];
#pragma unroll
    for (int g = 0; g < 2; ++g) {
      const unsigned short* qrow =
          qg + ((size_t)bh * 2048 + gq0 + qw + g * 16 + l15) * 64;
      qf[g][0] = *(const short8*)(qrow + quad * 8);
      qf[g][1] = *(const short8*)(qrow + quad * 8 + 32);
    }

    f32x4 acc_o[2][4];
    f32x4 acc_l[2];
#pragma unroll
    for (int g = 0; g < 2; ++g) {
      acc_l[g] = zero4;
#pragma unroll
      for (int nt = 0; nt < 4; ++nt) acc_o[g][nt] = zero4;
    }

    issue(0, 0);
    for (int kb = 0; kb < t1; ++kb) {
      const int cur = kb & 1;
      __syncthreads();  // drains global_load_lds for buffer `cur`
      if (kb + 1 < t1) issue(kb + 1, cur ^ 1);

      const unsigned short* kt = Ks[cur];
      const unsigned short* vt = Vt[cur];

      // ---- S^T = K Q^T : lane holds S^T[key=nt*16+quad*4+r][q=g*16+l15] ----
      f32x4 s[2][2];
      __builtin_amdgcn_s_setprio(1);
#pragma unroll
      for (int nt = 0; nt < 2; ++nt) {
        const unsigned short* kr = kt + (nt * 16 + l15) * 64;
        short8 kf0 = *(const short8*)(kr + kc0);
        short8 kf1 = *(const short8*)(kr + kc1);
#pragma unroll
        for (int g = 0; g < 2; ++g) {
          f32x4 cc = zero4;
          cc = __builtin_amdgcn_mfma_f32_16x16x32_bf16(kf0, qf[g][0], cc, 0, 0, 0);
          cc = __builtin_amdgcn_mfma_f32_16x16x32_bf16(kf1, qf[g][1], cc, 0, 0, 0);
          s[g][nt] = cc;
        }
      }
      __builtin_amdgcn_s_setprio(0);

      if ((kb >> 1) == qb) {  // diagonal tiles: causal mask
#pragma unroll
        for (int g = 0; g < 2; ++g) {
          int gq = gq0 + qw + g * 16 + l15;
#pragma unroll
          for (int nt = 0; nt < 2; ++nt) {
            int gk = kb * 32 + nt * 16 + quad * 4;
#pragma unroll
            for (int r = 0; r < 4; ++r)
              if (gk + r > gq) s[g][nt][r] = -INFINITY;
          }
        }
      }

      // ---- native exp2, truncation-packed P^T staging (8B writes) ----
#pragma unroll
      for (int g = 0; g < 2; ++g)
#pragma unroll
        for (int nt = 0; nt < 2; ++nt) {
          float e0 = __builtin_amdgcn_exp2f(s[g][nt][0]);
          float e1 = __builtin_amdgcn_exp2f(s[g][nt][1]);
          float e2 = __builtin_amdgcn_exp2f(s[g][nt][2]);
          float e3 = __builtin_amdgcn_exp2f(s[g][nt][3]);
          int cidx = ((g << 2) | (nt * 2 + (quad >> 1))) ^ m7;
          uint2 pk;
          pk.x = pack2bf_t(e0, e1);
          pk.y = pack2bf_t(e2, e3);
          *(uint2*)&pb[l15 * 64 + cidx * 8 + (quad & 1) * 4] = pk;
        }

      short8 pfa = *(const short8*)&pb[prd[0]];  // keys quad*8..+7, q=l15
      short8 pfb = *(const short8*)&pb[prd[1]];  // keys quad*8..+7, q=16+l15

      __builtin_amdgcn_s_setprio(1);
      // ---- denominator: acc_l += 1 . P^T (same bf16 P as numerator) ----
      acc_l[0] = __builtin_amdgcn_mfma_f32_16x16x32_bf16(ones8, pfa, acc_l[0], 0, 0, 0);
      acc_l[1] = __builtin_amdgcn_mfma_f32_16x16x32_bf16(ones8, pfb, acc_l[1], 0, 0, 0);

      // ---- O^T += V^T P^T : each V frag feeds both q-groups ----
#pragma unroll
      for (int nt = 0; nt < 4; ++nt) {
        const unsigned short* vr = vt + ((nt & 1) * 16 + l15) * 64 + vch[nt >> 1];
        short8 vf = *(const short8*)vr;
        acc_o[0][nt] = __builtin_amdgcn_mfma_f32_16x16x32_bf16(vf, pfa, acc_o[0][nt], 0, 0, 0);
        acc_o[1][nt] = __builtin_amdgcn_mfma_f32_16x16x32_bf16(vf, pfb, acc_o[1][nt], 0, 0, 0);
      }
      __builtin_amdgcn_s_setprio(0);
    }

    // all rows of acc_l[g] hold l(q=g*16+l15); no cross-lane reduction needed
    // full key range covered -> normalize and write directly
    const int b = bh >> 4;
    const int h = bh & 15;
#pragma unroll
    for (int g = 0; g < 2; ++g) {
      float inv_l = 1.0f / acc_l[g][0];
      unsigned short* orow =
          og + ((size_t)(b * 2048 + gq0 + qw + g * 16 + l15)) * 1024 + h * 64 +
          quad * 4;
#pragma unroll
      for (int nt = 0; nt < 4; ++nt) {
        *(unsigned*)(orow + nt * 16) =
            pack2bf(acc_o[g][nt][0] * inv_l, acc_o[g][nt][1] * inv_l);
        *(unsigned*)(orow + nt * 16 + 2) =
            pack2bf(acc_o[g][nt][2] * inv_l, acc_o[g][nt][3] * inv_l);
      }
    }

    // pass boundary: ensure partner wave's LDS reads are done before the
    // next pass's issue() overwrites buffer 0 (barrier drains lgkm+vm).
    if (pass == 0) __syncthreads();
  }
}

// ---------------------------------------------------------------------------
extern "C" void kernel_launch(void* const* d_in, const int* in_sizes, int n_in,
                              void* d_out, int out_size, void* d_ws,
                              size_t ws_size, hipStream_t stream) {
  const float* x = (const float*)d_in[0];
  // d_in[1] = causal mask (structure known, not read)
  const float* qkv_w = (const float*)d_in[2];
  const float* out_w = (const float*)d_in[3];
  const float* out_b = (const float*)d_in[4];
  float* out = (float*)d_out;

  // ws (ushort elems): xb 4M | wqkvT 3M | woT 1M | q 4M | k 4M | vt 4M |
  // ab 4M. (Partial buffers removed -- attn writes og directly.)
  unsigned short* xb = (unsigned short*)d_ws;
  unsigned short* wqkvT = xb + 4194304;
  unsigned short* woT = wqkvT + 3145728;
  unsigned short* qb16 = woT + 1048576;
  unsigned short* kb16 = qb16 + 4194304;
  unsigned short* vt16 = kb16 + 4194304;
  unsigned short* ab = vt16 + 4194304;

  prep<<<3072, 256, 0, stream>>>(x, xb, qkv_w, wqkvT, out_w, woT);
  gemm_qkv512<<<dim3(24, 32), 512, 0, stream>>>(xb, wqkvT, qb16, kb16, vt16);
  attn_mfma<<<dim3(32, 16), 128, 0, stream>>>(qb16, kb16, vt16, ab);
  gemm_out<<<dim3(8, 32), 512, 0, stream>>>(ab, woT, out_b, out);
}

// Round 10
// 187.547 us; speedup vs baseline: 1.0557x; 1.0557x over previous
//
#include <hip/hip_runtime.h>
#include <math.h>

// B=2, T=2048, D=1024, H=16, DH=64, M=B*T=4096
typedef __attribute__((ext_vector_type(8))) short short8;
typedef __attribute__((ext_vector_type(4))) float f32x4;

static __device__ __forceinline__ unsigned short f2bf(float f) {
  unsigned u = __builtin_bit_cast(unsigned, f);
  u += 0x7fffu + ((u >> 16) & 1u);  // RNE
  return (unsigned short)(u >> 16);
}
static __device__ __forceinline__ float bf2f(unsigned short h) {
  return __builtin_bit_cast(float, ((unsigned)h) << 16);
}
static __device__ __forceinline__ unsigned pack2bf(float a, float b) {
  return (unsigned)f2bf(a) | ((unsigned)f2bf(b) << 16);
}
// truncation pack (1 v_perm_b32): lo = trunc_bf16(a), hi = trunc_bf16(b)
static __device__ __forceinline__ unsigned pack2bf_t(float a, float b) {
  return __builtin_amdgcn_perm(__builtin_bit_cast(unsigned, b),
                               __builtin_bit_cast(unsigned, a), 0x07060302u);
}

typedef __attribute__((address_space(3))) unsigned short lds_us;
typedef __attribute__((address_space(1))) const unsigned short gbl_us;

static __device__ __forceinline__ void gld_lds16(const unsigned short* g,
                                                 unsigned short* l) {
  __builtin_amdgcn_global_load_lds((gbl_us*)g, (lds_us*)l, 16, 0, 0);
}

// ---------------------------------------------------------------------------
// prep: fused input conversion.
//  blocks [0,2048):    cast_x  fp32 x[4096*1024] -> bf16 xb
//  blocks [2048,2816): tcast   qkv_w [1024][3072] -> wqkvT [3072][1024]
//  blocks [2816,3072): tcast   out_w [1024][1024] -> woT  [1024][1024]
// ---------------------------------------------------------------------------
__global__ __launch_bounds__(256) void prep(const float* __restrict__ x,
                                            unsigned short* __restrict__ xb,
                                            const float* __restrict__ qkv_w,
                                            unsigned short* __restrict__ wqkvT,
                                            const float* __restrict__ out_w,
                                            unsigned short* __restrict__ woT) {
  __shared__ unsigned short T[64][68];
  const int blk = blockIdx.x;
  if (blk < 2048) {
    int i = (blk * 256 + threadIdx.x) * 8;
    float4 a = *(const float4*)(x + i);
    float4 b = *(const float4*)(x + i + 4);
    ushort4 u0 = {f2bf(a.x), f2bf(a.y), f2bf(a.z), f2bf(a.w)};
    ushort4 u1 = {f2bf(b.x), f2bf(b.y), f2bf(b.z), f2bf(b.w)};
    *(ushort4*)(xb + i) = u0;
    *(ushort4*)(xb + i + 4) = u1;
    return;
  }
  const float* in;
  unsigned short* out;
  int R, C, bx, by;
  if (blk < 2816) {
    in = qkv_w; out = wqkvT; R = 1024; C = 3072;
    bx = (blk - 2048) % 48; by = (blk - 2048) / 48;
  } else {
    in = out_w; out = woT; R = 1024; C = 1024;
    bx = (blk - 2816) % 16; by = (blk - 2816) / 16;
  }
  const int r0 = by * 64, c0 = bx * 64;
  const int tr = threadIdx.x >> 2;
  const int tc = (threadIdx.x & 3) * 16;
#pragma unroll
  for (int j = 0; j < 4; ++j) {
    float4 v = *(const float4*)(in + (size_t)(r0 + tr) * C + c0 + tc + j * 4);
    ushort4 u = {f2bf(v.x), f2bf(v.y), f2bf(v.z), f2bf(v.w)};
    *(ushort4*)&T[tr][tc + j * 4] = u;
  }
  __syncthreads();
  const int oc = tr;
#pragma unroll
  for (int g = 0; g < 4; ++g) {
    ushort4 u;
    u.x = T[tc + g * 4 + 0][oc];
    u.y = T[tc + g * 4 + 1][oc];
    u.z = T[tc + g * 4 + 2][oc];
    u.w = T[tc + g * 4 + 3][oc];
    *(ushort4*)(out + (size_t)(c0 + oc) * R + r0 + tc + g * 4) = u;
  }
}

// ---------------------------------------------------------------------------
// gemm_qkv512: C[4096,3072] = xb @ wqkvT^T, 128x128 tile, 8 waves (512
// threads), BK=32, double-buffered global_load_lds (1 barrier/iter).
// (R14-proven: same barrier count as R12's 4-wave version, 2x waves/CU.)
// ---------------------------------------------------------------------------
__global__ __launch_bounds__(512) void gemm_qkv512(
    const unsigned short* __restrict__ A, const unsigned short* __restrict__ BT,
    unsigned short* __restrict__ qo, unsigned short* __restrict__ ko,
    unsigned short* __restrict__ vo) {
  __shared__ unsigned short As[2][4096];
  __shared__ unsigned short Bs[2][4096];
  const int tid = threadIdx.x;
  const int w = tid >> 6;
  const int lane = tid & 63;
  const int l15 = lane & 15;
  const int quad = lane >> 4;
  const int wm = w >> 2;       // 0..1 : row half
  const int wn = w & 3;        // 0..3 : column group
  const int m0 = blockIdx.y * 128;
  const int n0 = blockIdx.x * 128;

  f32x4 acc[4][2];
  const f32x4 zero4 = {0.f, 0.f, 0.f, 0.f};
#pragma unroll
  for (int mt = 0; mt < 4; ++mt)
#pragma unroll
    for (int nt = 0; nt < 2; ++nt) acc[mt][nt] = zero4;

  // staging: 512 chunks per matrix, 1 A + 1 B chunk per thread
  const int srow = tid >> 2;
  const int skch = (tid & 3) ^ ((srow >> 1) & 3);
  const int coff = tid * 8;
  const unsigned short* gA = A + (size_t)(m0 + srow) * 1024 + skch * 8;
  const unsigned short* gB = BT + (size_t)(n0 + srow) * 1024 + skch * 8;

  const int swz = (quad ^ ((l15 >> 1) & 3)) * 8;
  int aoff[4], boff[2];
#pragma unroll
  for (int t = 0; t < 4; ++t)
    aoff[t] = (wm * 64 + t * 16 + l15) * 32 + swz;
#pragma unroll
  for (int t = 0; t < 2; ++t)
    boff[t] = ((wn >> 1) * 64 + (wn & 1) * 16 + t * 32 + l15) * 32 + swz;

  auto issue = [&](int k0, int buf) {
    gld_lds16(gA + k0, &As[buf][coff]);
    gld_lds16(gB + k0, &Bs[buf][coff]);
  };

  issue(0, 0);
  for (int it = 0; it < 32; ++it) {
    const int cur = it & 1;
    __syncthreads();  // drains the prefetch issued one full iteration ago
    if (it + 1 < 32) issue((it + 1) * 32, cur ^ 1);

    short8 af[4], bf[2];
#pragma unroll
    for (int t = 0; t < 4; ++t) af[t] = *(const short8*)(&As[cur][aoff[t]]);
#pragma unroll
    for (int t = 0; t < 2; ++t) bf[t] = *(const short8*)(&Bs[cur][boff[t]]);
#pragma unroll
    for (int mt = 0; mt < 4; ++mt)
#pragma unroll
      for (int nt = 0; nt < 2; ++nt)
        acc[mt][nt] =
            __builtin_amdgcn_mfma_f32_16x16x32_bf16(af[mt], bf[nt], acc[mt][nt], 0, 0, 0);
  }

  const int b = m0 >> 11;
  const int ngrp = n0 + (wn >> 1) * 64;  // 64-aligned (which, head) group
  const int which = ngrp >> 10;
  const int h = (ngrp & 1023) >> 6;
  const int bh = b * 16 + h;
  if (which < 2) {
    unsigned short* dst = which ? ko : qo;
    // q pre-scale: 1/sqrt(64) * log2(e) so attention scores feed exp2.
    const float qs = (which == 0) ? 0.1803368801111f : 1.0f;
    const int p = (wn & 1) * 16 + l15;  // RoPE freq index, < 32
    // 10000^(-p/32) / 2pi (angle in revolutions for v_sin/v_cos)
    float inv = __builtin_amdgcn_exp2f((float)p * -0.41524101186f) *
                0.15915494309f;
#pragma unroll
    for (int mt = 0; mt < 4; ++mt)
#pragma unroll
      for (int r = 0; r < 4; ++r) {
        int t = (m0 + wm * 64 + mt * 16 + quad * 4 + r) & 2047;
        float rv = __builtin_amdgcn_fractf((float)t * inv);
        float s = __builtin_amdgcn_sinf(rv);
        float c = __builtin_amdgcn_cosf(rv);
        float x0 = acc[mt][0][r], x1 = acc[mt][1][r];
        size_t rowoff = ((size_t)bh * 2048 + t) * 64;
        dst[rowoff + p]      = f2bf((x0 * c - x1 * s) * qs);
        dst[rowoff + p + 32] = f2bf((x1 * c + x0 * s) * qs);
      }
  } else {
#pragma unroll
    for (int mt = 0; mt < 4; ++mt) {
      int t0 = (m0 + wm * 64 + mt * 16 + quad * 4) & 2047;
#pragma unroll
      for (int nt = 0; nt < 2; ++nt) {
        int dh = (wn & 1) * 16 + nt * 32 + l15;
        ushort4 st = {f2bf(acc[mt][nt][0]), f2bf(acc[mt][nt][1]),
                      f2bf(acc[mt][nt][2]), f2bf(acc[mt][nt][3])};
        *(ushort4*)(vo + ((size_t)bh * 64 + dh) * 2048 + t0) = st;
      }
    }
  }
}

// ---------------------------------------------------------------------------
// gemm_out R21: out[4096,1024] = ab @ woT^T + bias, fp32 store.
// gemm_qkv512 structure: 128x128 tile, 8 waves (512 thr), BK=32, dbuf
// global_load_lds, 1 barrier/iter. Grid (8,32) = 256 blocks = 1/CU.
// R21-proven (+2.4us vs the 128x64 4-wave version).
// ---------------------------------------------------------------------------
__global__ __launch_bounds__(512) void gemm_out(
    const unsigned short* __restrict__ A, const unsigned short* __restrict__ BT,
    const float* __restrict__ bias, float* __restrict__ out) {
  __shared__ unsigned short As[2][4096];
  __shared__ unsigned short Bs[2][4096];
  const int tid = threadIdx.x;
  const int w = tid >> 6;
  const int lane = tid & 63;
  const int l15 = lane & 15;
  const int quad = lane >> 4;
  const int wm = w >> 2;       // 0..1 : row half
  const int wn = w & 3;        // 0..3 : column group
  const int m0 = blockIdx.y * 128;
  const int n0 = blockIdx.x * 128;

  f32x4 acc[4][2];
  const f32x4 zero4 = {0.f, 0.f, 0.f, 0.f};
#pragma unroll
  for (int mt = 0; mt < 4; ++mt)
#pragma unroll
    for (int nt = 0; nt < 2; ++nt) acc[mt][nt] = zero4;

  // staging: 512 chunks per matrix, 1 A + 1 B chunk per thread
  const int srow = tid >> 2;
  const int skch = (tid & 3) ^ ((srow >> 1) & 3);
  const int coff = tid * 8;
  const unsigned short* gA = A + (size_t)(m0 + srow) * 1024 + skch * 8;
  const unsigned short* gB = BT + (size_t)(n0 + srow) * 1024 + skch * 8;

  const int swz = (quad ^ ((l15 >> 1) & 3)) * 8;
  int aoff[4], boff[2];
#pragma unroll
  for (int t = 0; t < 4; ++t)
    aoff[t] = (wm * 64 + t * 16 + l15) * 32 + swz;
#pragma unroll
  for (int t = 0; t < 2; ++t)
    boff[t] = ((wn >> 1) * 64 + (wn & 1) * 16 + t * 32 + l15) * 32 + swz;

  auto issue = [&](int k0, int buf) {
    gld_lds16(gA + k0, &As[buf][coff]);
    gld_lds16(gB + k0, &Bs[buf][coff]);
  };

  issue(0, 0);
  for (int it = 0; it < 32; ++it) {
    const int cur = it & 1;
    __syncthreads();  // drains the prefetch issued one full iteration ago
    if (it + 1 < 32) issue((it + 1) * 32, cur ^ 1);

    short8 af[4], bf[2];
#pragma unroll
    for (int t = 0; t < 4; ++t) af[t] = *(const short8*)(&As[cur][aoff[t]]);
#pragma unroll
    for (int t = 0; t < 2; ++t) bf[t] = *(const short8*)(&Bs[cur][boff[t]]);
#pragma unroll
    for (int mt = 0; mt < 4; ++mt)
#pragma unroll
      for (int nt = 0; nt < 2; ++nt)
        acc[mt][nt] =
            __builtin_amdgcn_mfma_f32_16x16x32_bf16(af[mt], bf[nt], acc[mt][nt], 0, 0, 0);
  }

  // epilogue: cols n = n0 + (wn>>1)*64 + (wn&1)*16 + nt*32 + l15 (matches boff)
  const int nb2 = n0 + (wn >> 1) * 64 + (wn & 1) * 16;
  float bv[2];
#pragma unroll
  for (int nt = 0; nt < 2; ++nt) bv[nt] = bias[nb2 + nt * 32 + l15];
#pragma unroll
  for (int mt = 0; mt < 4; ++mt)
#pragma unroll
    for (int r = 0; r < 4; ++r) {
      int m = m0 + wm * 64 + mt * 16 + quad * 4 + r;
      float* orow = out + (size_t)m * 1024 + nb2 + l15;
      orow[0]  = acc[mt][0][r] + bv[0];
      orow[32] = acc[mt][1][r] + bv[1];
    }
}

// ---------------------------------------------------------------------------
// Causal flash attention, bf16 MFMA. R25 = R21 (measured best, 187.94us);
// R24 submission hit an infra failure ("container failed twice"), resubmit.
// Final attn model (fits R14-R23): two-regime makespan.
//  (a) per-block serial latency lambda ~2000-2150 cyc/iter -- binds when a
//      block is long (R22: 64 iters -> 52us; R23: 66 -> 59us, exact);
//  (b) per-CU shared ceiling ~740 cyc per 64qx32k unit at >=4 blocks/CU
//      (R15/16/17/20/21: 132 units/CU -> 40.7us, all within 3%).
// Chunking bounds the critical path (max block 18 iters x lambda = 16us <<
// 40.7) so the ceiling dominates -- that is why R21 is optimal and both
// no-partial variants (R22/R23) regressed. The combine kernel is the
// necessary price. Structure: 32q/wave, 2 waves/block, 32-key tiles, dbuf
// global_load_lds + full-drain __syncthreads, 8-chunk row&7 XOR swizzles,
// per-wave Ps, 80 heavy-first slots/bh, partials for qb>=8.
// Grid x=bh -> XCD=bh%8 (L2 locality).
// ---------------------------------------------------------------------------
__global__ __launch_bounds__(128, 4) void attn_mfma(
    const unsigned short* __restrict__ qg, const unsigned short* __restrict__ kg,
    const unsigned short* __restrict__ vtg, unsigned short* __restrict__ og,
    unsigned short* __restrict__ OpA,  // partials pidx 16..71 (56/bh)
    unsigned short* __restrict__ OpB,  // partials pidx 0..15 (16/bh)
    float* __restrict__ Lpart) {
  // Ks: [key 32][128B] rows, chunk c holds dh-chunk c^(key&7)
  // Vt: [r 32][128B] rows, chunk c -> lc=c^(r&7): dh=(lc>>2)*32+r, t-chunk lc&3
  // Ps: per-wave [q&15 16][128B], chunk c -> lc=c^(q&7): half lc>>2 = q-group,
  //     key-chunk lc&3 (8 keys, two 8B halves)
  __shared__ unsigned short Ks[2][2048];  // 8192 B
  __shared__ unsigned short Vt[2][2048];  // 8192 B
  __shared__ unsigned short Ps[2][1024];  // 4096 B (per wave 2KB: 32q x 32k)
  const int bh = blockIdx.x;    // x = bh -> XCD = bh%8 (L2 locality)
  const int slot = blockIdx.y;  // y = slot, heavy-first
  int qb, chunk;
  if (slot < 32) {
    qb = 24 + (slot & 7);
    chunk = slot >> 3;
  } else if (slot < 56) {
    int s = slot - 32;
    qb = 16 + (s & 7);
    chunk = s >> 3;
  } else if (slot < 72) {
    int s = slot - 56;
    qb = 8 + (s & 7);
    chunk = s >> 3;
  } else {
    qb = slot - 72;
    chunk = 0;
  }
  const int n = qb >= 24 ? 4 : (qb >= 16 ? 3 : (qb >= 8 ? 2 : 1));
  // key range in 32-key tiles: [0, 2*(qb+1)) split into n chunks
  const int t0 = chunk * 2 * (qb + 1) / n;
  const int t1 = (chunk + 1) * 2 * (qb + 1) / n;

  const int tid = threadIdx.x;
  const int w = tid >> 6;   // 0..1
  const int lane = tid & 63;
  const int l15 = lane & 15;
  const int quad = lane >> 4;
  const int m7 = l15 & 7;

  const int gq0 = qb * 64;
  const int qw = w * 32;  // wave's first query within block

  // Q fragments for two 16-query groups
  short8 qf[2][2];
#pragma unroll
  for (int g = 0; g < 2; ++g) {
    const unsigned short* qrow =
        qg + ((size_t)bh * 2048 + gq0 + qw + g * 16 + l15) * 64;
    qf[g][0] = *(const short8*)(qrow + quad * 8);
    qf[g][1] = *(const short8*)(qrow + quad * 8 + 32);
  }

  f32x4 acc_o[2][4];
  f32x4 acc_l[2];
  const f32x4 zero4 = {0.f, 0.f, 0.f, 0.f};
#pragma unroll
  for (int g = 0; g < 2; ++g) {
    acc_l[g] = zero4;
#pragma unroll
    for (int nt = 0; nt < 4; ++nt) acc_o[g][nt] = zero4;
  }
  const short one_bf = (short)0x3F80;  // bf16 1.0
  const short8 ones8 = {one_bf, one_bf, one_bf, one_bf,
                        one_bf, one_bf, one_bf, one_bf};

  const unsigned short* kbase = kg + (size_t)bh * 2048 * 64;
  const unsigned short* vtbase = vtg + (size_t)bh * 64 * 2048;
  unsigned short* pb = Ps[w];

  // staging: 256 16B-chunks per matrix, 2 K + 2 V per thread (128 threads)
  int doff[2], koff[2], voff[2];
#pragma unroll
  for (int i = 0; i < 2; ++i) {
    int d = i * 128 + tid;
    doff[i] = d * 8;
    int r = d >> 3;
    int lc = (d & 7) ^ (r & 7);
    koff[i] = r * 64 + lc * 8;               // key r, dh-chunk lc
    int dh = (lc >> 2) * 32 + r;
    voff[i] = dh * 2048 + (lc & 3) * 8;      // dh row, t-chunk lc&3
  }

  auto issue = [&](int kb, int buf) {
#pragma unroll
    for (int i = 0; i < 2; ++i) {
      gld_lds16(kbase + kb * 2048 + koff[i], &Ks[buf][doff[i]]);
      gld_lds16(vtbase + voff[i] + kb * 32, &Vt[buf][doff[i]]);
    }
  };

  const int kc0 = ((quad ^ m7) & 7) * 8;  // K chunk for dh=quad*8
  const int kc1 = kc0 ^ 32;               // K chunk for dh=quad*8+32
  int prd[2], vch[2];
#pragma unroll
  for (int g = 0; g < 2; ++g) prd[g] = l15 * 64 + (((g << 2) | quad) ^ m7) * 8;
#pragma unroll
  for (int h = 0; h < 2; ++h) vch[h] = (((h << 2) | quad) ^ m7) * 8;

  issue(t0, 0);
  for (int kb = t0; kb < t1; ++kb) {
    const int cur = (kb - t0) & 1;
    __syncthreads();  // drains global_load_lds for buffer `cur`
    if (kb + 1 < t1) issue(kb + 1, cur ^ 1);

    const unsigned short* kt = Ks[cur];
    const unsigned short* vt = Vt[cur];

    // ---- S^T = K Q^T : lane holds S^T[key=nt*16+quad*4+r][q=g*16+l15] ----
    f32x4 s[2][2];
    __builtin_amdgcn_s_setprio(1);
#pragma unroll
    for (int nt = 0; nt < 2; ++nt) {
      const unsigned short* kr = kt + (nt * 16 + l15) * 64;
      short8 kf0 = *(const short8*)(kr + kc0);
      short8 kf1 = *(const short8*)(kr + kc1);
#pragma unroll
      for (int g = 0; g < 2; ++g) {
        f32x4 cc = zero4;
        cc = __builtin_amdgcn_mfma_f32_16x16x32_bf16(kf0, qf[g][0], cc, 0, 0, 0);
        cc = __builtin_amdgcn_mfma_f32_16x16x32_bf16(kf1, qf[g][1], cc, 0, 0, 0);
        s[g][nt] = cc;
      }
    }
    __builtin_amdgcn_s_setprio(0);

    if ((kb >> 1) == qb) {  // diagonal tiles: causal mask
#pragma unroll
      for (int g = 0; g < 2; ++g) {
        int gq = gq0 + qw + g * 16 + l15;
#pragma unroll
        for (int nt = 0; nt < 2; ++nt) {
          int gk = kb * 32 + nt * 16 + quad * 4;
#pragma unroll
          for (int r = 0; r < 4; ++r)
            if (gk + r > gq) s[g][nt][r] = -INFINITY;
        }
      }
    }

    // ---- native exp2, truncation-packed P^T staging (8B writes) ----
#pragma unroll
    for (int g = 0; g < 2; ++g)
#pragma unroll
      for (int nt = 0; nt < 2; ++nt) {
        float e0 = __builtin_amdgcn_exp2f(s[g][nt][0]);
        float e1 = __builtin_amdgcn_exp2f(s[g][nt][1]);
        float e2 = __builtin_amdgcn_exp2f(s[g][nt][2]);
        float e3 = __builtin_amdgcn_exp2f(s[g][nt][3]);
        int cidx = ((g << 2) | (nt * 2 + (quad >> 1))) ^ m7;
        uint2 pk;
        pk.x = pack2bf_t(e0, e1);
        pk.y = pack2bf_t(e2, e3);
        *(uint2*)&pb[l15 * 64 + cidx * 8 + (quad & 1) * 4] = pk;
      }

    short8 pfa = *(const short8*)&pb[prd[0]];  // keys quad*8..+7, q=l15
    short8 pfb = *(const short8*)&pb[prd[1]];  // keys quad*8..+7, q=16+l15

    __builtin_amdgcn_s_setprio(1);
    // ---- denominator: acc_l += 1 . P^T (same bf16 P as numerator) ----
    acc_l[0] = __builtin_amdgcn_mfma_f32_16x16x32_bf16(ones8, pfa, acc_l[0], 0, 0, 0);
    acc_l[1] = __builtin_amdgcn_mfma_f32_16x16x32_bf16(ones8, pfb, acc_l[1], 0, 0, 0);

    // ---- O^T += V^T P^T : each V frag feeds both q-groups ----
#pragma unroll
    for (int nt = 0; nt < 4; ++nt) {
      const unsigned short* vr = vt + ((nt & 1) * 16 + l15) * 64 + vch[nt >> 1];
      short8 vf = *(const short8*)vr;
      acc_o[0][nt] = __builtin_amdgcn_mfma_f32_16x16x32_bf16(vf, pfa, acc_o[0][nt], 0, 0, 0);
      acc_o[1][nt] = __builtin_amdgcn_mfma_f32_16x16x32_bf16(vf, pfb, acc_o[1][nt], 0, 0, 0);
    }
    __builtin_amdgcn_s_setprio(0);
  }

  // all rows of acc_l[g] hold l(q=g*16+l15); no cross-lane reduction needed
  float lsum[2] = {acc_l[0][0], acc_l[1][0]};

  if (n == 1) {
    // single chunk covers full key range -> normalize and write directly
    const int b = bh >> 4;
    const int h = bh & 15;
#pragma unroll
    for (int g = 0; g < 2; ++g) {
      float inv_l = 1.0f / lsum[g];
      unsigned short* orow =
          og + ((size_t)(b * 2048 + gq0 + qw + g * 16 + l15)) * 1024 + h * 64 +
          quad * 4;
#pragma unroll
      for (int nt = 0; nt < 4; ++nt) {
        *(unsigned*)(orow + nt * 16) =
            pack2bf(acc_o[g][nt][0] * inv_l, acc_o[g][nt][1] * inv_l);
        *(unsigned*)(orow + nt * 16 + 2) =
            pack2bf(acc_o[g][nt][2] * inv_l, acc_o[g][nt][3] * inv_l);
      }
    }
  } else {
    // partial: unnormalized bf16 O + fp32 l
    const int pidx = (qb < 16) ? (qb - 8) * 2 + chunk
                               : (qb < 24) ? 16 + (qb - 16) * 3 + chunk
                                           : 40 + (qb - 24) * 4 + chunk;
    unsigned short* obase = (pidx < 16)
                                ? OpB + ((size_t)(bh * 16 + pidx)) * 4096
                                : OpA + ((size_t)(bh * 56 + (pidx - 16))) * 4096;
#pragma unroll
    for (int g = 0; g < 2; ++g) {
      unsigned short* orow = obase + (qw + g * 16 + l15) * 64 + quad * 4;
#pragma unroll
      for (int nt = 0; nt < 4; ++nt) {
        *(unsigned*)(orow + nt * 16) = pack2bf(acc_o[g][nt][0], acc_o[g][nt][1]);
        *(unsigned*)(orow + nt * 16 + 2) = pack2bf(acc_o[g][nt][2], acc_o[g][nt][3]);
      }
      if (quad == 0)
        Lpart[(bh * 72 + pidx) * 64 + qw + g * 16 + l15] = lsum[g];
    }
  }
}

// ---------------------------------------------------------------------------
// attn_combine: O = (sum_c P_c) / (sum_c l_c) for qb in [8,32). 4 dh/thread.
// ---------------------------------------------------------------------------
__global__ __launch_bounds__(256) void attn_combine(
    const unsigned short* __restrict__ OpA, const unsigned short* __restrict__ OpB,
    const float* __restrict__ Lpart, unsigned short* __restrict__ og) {
  int i = blockIdx.x * 256 + threadIdx.x;  // 786432 total
  int dh = (i & 15) * 4;
  int q = (i >> 4) & 63;
  int idx = i >> 10;  // 0..767 = bh*24 + qr
  int bh = idx / 24;
  int qr = idx - bh * 24;
  int qb = 8 + qr;
  int count = qr < 8 ? 2 : (qr < 16 ? 3 : 4);
  int pstart = qr < 8 ? qr * 2 : (qr < 16 ? 16 + (qr - 8) * 3 : 40 + (qr - 16) * 4);
  float o0 = 0.f, o1 = 0.f, o2 = 0.f, o3 = 0.f, l = 0.f;
  for (int c = 0; c < count; ++c) {
    int pidx = pstart + c;
    const unsigned short* obase =
        (pidx < 16) ? OpB + ((size_t)(bh * 16 + pidx)) * 4096
                    : OpA + ((size_t)(bh * 56 + (pidx - 16))) * 4096;
    ushort4 a = *(const ushort4*)(obase + q * 64 + dh);
    o0 += bf2f(a.x);
    o1 += bf2f(a.y);
    o2 += bf2f(a.z);
    o3 += bf2f(a.w);
    l += Lpart[(bh * 72 + pidx) * 64 + q];
  }
  float inv = 1.0f / l;
  int bb = bh >> 4, h = bh & 15;
  int t = qb * 64 + q;
  unsigned short* orow = og + ((size_t)(bb * 2048 + t)) * 1024 + h * 64 + dh;
  *(unsigned*)(orow) = pack2bf(o0 * inv, o1 * inv);
  *(unsigned*)(orow + 2) = pack2bf(o2 * inv, o3 * inv);
}

// ---------------------------------------------------------------------------
extern "C" void kernel_launch(void* const* d_in, const int* in_sizes, int n_in,
                              void* d_out, int out_size, void* d_ws,
                              size_t ws_size, hipStream_t stream) {
  const float* x = (const float*)d_in[0];
  // d_in[1] = causal mask (structure known, not read)
  const float* qkv_w = (const float*)d_in[2];
  const float* out_w = (const float*)d_in[3];
  const float* out_b = (const float*)d_in[4];
  float* out = (float*)d_out;

  // ws (ushort elems): xb 4M | wqkvT 3M | woT 1M | q 4M | k 4M | vt 4M |
  // ab 4M | OpB 4M | Lpart 147456 fp32.
  // OpA (7,340,032 ushorts = 56 partials/bh) ALIASES xb+wqkvT exactly --
  // both dead once gemm_qkv has run; woT (used later by gemm_out) untouched.
  unsigned short* xb = (unsigned short*)d_ws;
  unsigned short* wqkvT = xb + 4194304;
  unsigned short* woT = wqkvT + 3145728;
  unsigned short* qb16 = woT + 1048576;
  unsigned short* kb16 = qb16 + 4194304;
  unsigned short* vt16 = kb16 + 4194304;
  unsigned short* ab = vt16 + 4194304;
  unsigned short* OpB = ab + 4194304;
  float* Lpart = (float*)(OpB + 4194304);
  unsigned short* OpA = xb;  // alias (see above)

  prep<<<3072, 256, 0, stream>>>(x, xb, qkv_w, wqkvT, out_w, woT);
  gemm_qkv512<<<dim3(24, 32), 512, 0, stream>>>(xb, wqkvT, qb16, kb16, vt16);
  attn_mfma<<<dim3(32, 80), 128, 0, stream>>>(qb16, kb16, vt16, ab, OpA, OpB,
                                              Lpart);
  attn_combine<<<3072, 256, 0, stream>>>(OpA, OpB, Lpart, ab);
  gemm_out<<<dim3(8, 32), 512, 0, stream>>>(ab, woT, out_b, out);
}